// Round 2
// baseline (1928.992 us; speedup 1.0000x reference)
//
#include <hip/hip_runtime.h>
#include <stdint.h>

#define NTOK 16384   // B*S = 4*4096
#define DIN 512
#define DOUT 512
#define KE 8
#define BM 128
#define BN 128
#define BK 64

#define GATE_BLOCKS 4096           // 1 token/wave, 4 waves/block
#define WCONV_BLOCKS 1024          // 2M elements / (256*8)

typedef unsigned short u16;
typedef u16 u16x8 __attribute__((ext_vector_type(8)));
typedef __bf16 bf16x8 __attribute__((ext_vector_type(8)));
typedef float f32x4 __attribute__((ext_vector_type(4)));
typedef float f32x16 __attribute__((ext_vector_type(16)));

__device__ __forceinline__ u16 f2bf(float f) {
  union { float f; unsigned u; } v; v.f = f;
  unsigned r = v.u + 0x7FFFu + ((v.u >> 16) & 1u);   // RNE; inputs are finite
  return (u16)(r >> 16);
}

// async global->LDS, 16B per lane; LDS dest is wave-uniform base + lane*16
#define GLOAD_LDS16(gp, lp)                                              \
  __builtin_amdgcn_global_load_lds(                                     \
      (__attribute__((address_space(1))) void*)(gp),                    \
      (__attribute__((address_space(3))) void*)(lp), 16, 0, 0)

// ---------------------------------------------------------------------------
// Kernel 1a: gating softmax + x fp32->bf16 cast. ONE token per wave (max
// parallelism; v1/v2 had 2/8 sequential tokens and both sat at ~91us —
// split from wcast so rocprof shows each component separately).
// Coeffs written TRANSPOSED: coeffsT[e][tok].
// ---------------------------------------------------------------------------
__global__ __launch_bounds__(256) void gate_kernel(
    const float* __restrict__ x, const float* __restrict__ mw,
    const float* __restrict__ mb, u16* __restrict__ xbf,
    float* __restrict__ coeffsT) {
  const int tid = threadIdx.x;
  const int wave = tid >> 6, lane = tid & 63;
  const int tok = blockIdx.x * 4 + wave;

  // mixer weight slice for this lane, in registers (broadcast loads)
  float mwr[KE][8];
#pragma unroll
  for (int k = 0; k < KE; ++k) {
    const float* wr = &mw[k * DIN + lane * 8];
    const float4 w0 = *(const float4*)wr;
    const float4 w1 = *(const float4*)(wr + 4);
    mwr[k][0] = w0.x; mwr[k][1] = w0.y; mwr[k][2] = w0.z; mwr[k][3] = w0.w;
    mwr[k][4] = w1.x; mwr[k][5] = w1.y; mwr[k][6] = w1.z; mwr[k][7] = w1.w;
  }
  float mbr[KE];
#pragma unroll
  for (int k = 0; k < KE; ++k) mbr[k] = mb[k];

  const float* xr = x + (size_t)tok * DIN + lane * 8;
  const float4 xa = *(const float4*)xr;
  const float4 xb = *(const float4*)(xr + 4);

  u16x8 p;
  p[0] = f2bf(xa.x); p[1] = f2bf(xa.y); p[2] = f2bf(xa.z); p[3] = f2bf(xa.w);
  p[4] = f2bf(xb.x); p[5] = f2bf(xb.y); p[6] = f2bf(xb.z); p[7] = f2bf(xb.w);
  *(u16x8*)(xbf + (size_t)tok * DIN + lane * 8) = p;

  float lg[KE];
#pragma unroll
  for (int k = 0; k < KE; ++k) {
    lg[k] = xa.x * mwr[k][0] + xa.y * mwr[k][1] + xa.z * mwr[k][2] +
            xa.w * mwr[k][3] + xb.x * mwr[k][4] + xb.y * mwr[k][5] +
            xb.z * mwr[k][6] + xb.w * mwr[k][7];
  }
#pragma unroll
  for (int off = 32; off; off >>= 1)
#pragma unroll
    for (int k = 0; k < KE; ++k) lg[k] += __shfl_xor(lg[k], off);

#pragma unroll
  for (int k = 0; k < KE; ++k) lg[k] += mbr[k];
  float mx = lg[0];
#pragma unroll
  for (int k = 1; k < KE; ++k) mx = fmaxf(mx, lg[k]);
  float s = 0.f;
#pragma unroll
  for (int k = 0; k < KE; ++k) { lg[k] = __expf(lg[k] - mx); s += lg[k]; }
  const float inv = 1.f / s;
  if (lane == 0) {
#pragma unroll
    for (int k = 0; k < KE; ++k) coeffsT[(size_t)k * NTOK + tok] = lg[k] * inv;
  }
}

// ---------------------------------------------------------------------------
// Kernel 1b: expert-weight fp32->bf16 cast (8 elements/thread).
// ---------------------------------------------------------------------------
__global__ __launch_bounds__(256) void wcast_kernel(
    const float* __restrict__ ew, u16* __restrict__ wbf) {
  const size_t i = ((size_t)blockIdx.x * 256 + threadIdx.x) * 8;
  const float4 a = *(const float4*)&ew[i];
  const float4 b = *(const float4*)&ew[i + 4];
  u16x8 p;
  p[0] = f2bf(a.x); p[1] = f2bf(a.y); p[2] = f2bf(a.z); p[3] = f2bf(a.w);
  p[4] = f2bf(b.x); p[5] = f2bf(b.y); p[6] = f2bf(b.z); p[7] = f2bf(b.w);
  *(u16x8*)&wbf[i] = p;
}

// ---------------------------------------------------------------------------
// Kernel 2: main MoE GEMM. v3: h-outer (8 chunks of K=64), e-inner.
// Why (R1 rocprof): e-outer re-staged A 8x -> FETCH 269 MB, 3.3 TB/s on
// fabric, vmcnt(0) drains waiting on LLC latency. Now A staged ONCE per
// chunk (A traffic 512->64 MB); B streams per (h,e) but each XCD's B slice
// is 1 MB -> L2-resident hits. Per-(h,e) partial folded immediately
// (fold is linear): acc += c_e * part  (+bias once at h==7).
// MFMA: 32x32x16 (2382 vs 2075 TF ceiling, half the instructions).
// Pipeline: minimum 2-phase, ONE barrier per (h,e): stage B_next ->
// Bs[t+1&1]; compute Bs[t&1]; barrier. A single-buffered: af regs read only
// at e==0, A_{h+1} staged at e==1 (barrier-separated, no extra syncs).
// LDS: As 16K + Bs 2x16K + cS 4K + ebS 4K = 56 KB -> 2 blocks/CU.
// Grid 512 = exactly 2/CU, no tail. XOR-swizzled LDS (both-sides rule).
// ---------------------------------------------------------------------------
__global__ __launch_bounds__(256, 2) void moe_gemm_kernel(
    const u16* __restrict__ xbf, const u16* __restrict__ wbf,
    const float* __restrict__ coeffsT, const float* __restrict__ ebias,
    float* __restrict__ out) {
  __shared__ __align__(16) u16 As[BM * BK];        // 16 KB, single buffer
  __shared__ __align__(16) u16 Bs[2][BN * BK];     // 2 x 16 KB
  __shared__ __align__(16) float cS[KE * BM];      // 4 KB  coeffs slice
  __shared__ __align__(16) float ebS[KE * BN];     // 4 KB  bias slice

  const int tid = threadIdx.x;
  const int wave = tid >> 6, lane = tid & 63;

  // XCD swizzle: b&7 = xcd. Each XCD-pair owns one n-column -> its 1 MB
  // B slice (8 experts x 128 cols x 512 K bf16) is L2-resident.
  const int b = blockIdx.x;
  const int xcd = b & 7, s = b >> 3;            // s in [0,64)
  const int m0 = ((xcd & 1) * 64 + s) * BM;
  const int n0 = (xcd >> 1) * BN;

  const int wm = (wave >> 1) * 64;   // wave's row offset: {0,64}
  const int wn = (wave & 1) * 64;    // wave's col offset: {0,64}

  const int l31 = lane & 31, l5 = lane >> 5, l7 = lane & 7;

  // staging: each GLOAD covers 8 rows x 64 cols (1 KB). SOURCE col chunk
  // XOR-swizzled: LDS slot s of row r = global chunk s^(r&7).
  const int lrow = lane >> 3;
  const int scol = ((lane & 7) ^ lrow) * 8;
  const u16* aBase = xbf + (size_t)(m0 + wave * 32 + lrow) * DIN + scol;
  const u16* bBase = wbf + (size_t)(n0 + wave * 32 + lrow) * DIN + scol;

  // ---- prologue staging: A_0, B_(h0,e0), coeffs slice, bias slice ----
#pragma unroll
  for (int j = 0; j < 4; ++j)
    GLOAD_LDS16(aBase + (size_t)(j * 8) * DIN, &As[(wave * 32 + j * 8) * BK]);
#pragma unroll
  for (int j = 0; j < 4; ++j)
    GLOAD_LDS16(bBase + (size_t)(j * 8) * DIN, &Bs[0][(wave * 32 + j * 8) * BK]);
  // cS[e][i] = coeffsT[e][m0+i], ebS[e][i] = ebias[e][n0+i]; wave w covers
  // e in {2w, 2w+1}: LDS idx w*256 + lane*4 == (2w+l5)*128 + l31*4.
  GLOAD_LDS16(coeffsT + (size_t)(wave * 2 + l5) * NTOK + m0 + l31 * 4,
              &cS[wave * 256]);
  GLOAD_LDS16(ebias + (size_t)(wave * 2 + l5) * DOUT + n0 + l31 * 4,
              &ebS[wave * 256]);
  __syncthreads();

  const f32x16 vz = {};
  f32x16 acc[2][2] = {{vz, vz}, {vz, vz}};
  bf16x8 af[4][2];   // A fragments for current h chunk: [ks][mi]

  for (int h = 0; h < 8; ++h) {
    for (int e = 0; e < KE; ++e) {
      const int t = h * 8 + e;
      // ---- STAGE next B tile (and A_{h+1} at e==1) ----
      if (t < 63) {
        const int tn = t + 1;
        const int en = tn & 7, hn = tn >> 3;
        const u16* bS = bBase + (size_t)en * (DOUT * DIN) + (size_t)hn * 64;
#pragma unroll
        for (int j = 0; j < 4; ++j)
          GLOAD_LDS16(bS + (size_t)(j * 8) * DIN,
                      &Bs[tn & 1][(wave * 32 + j * 8) * BK]);
      }
      if (e == 1 && h < 7) {
        const u16* aS = aBase + (size_t)(h + 1) * 64;
#pragma unroll
        for (int j = 0; j < 4; ++j)
          GLOAD_LDS16(aS + (size_t)(j * 8) * DIN,
                      &As[(wave * 32 + j * 8) * BK]);
      }

      // ---- COMPUTE from Bs[t&1] (and load af at e==0) ----
      if (e == 0) {
#pragma unroll
        for (int ks = 0; ks < 4; ++ks)
#pragma unroll
          for (int mi = 0; mi < 2; ++mi)
            af[ks][mi] = *(const bf16x8*)
                &As[(wm + mi * 32 + l31) * BK + (((ks * 2 + l5) ^ l7)) * 8];
      }
      const u16* Bp = Bs[t & 1];
      f32x16 part[2][2];
#pragma unroll
      for (int ks = 0; ks < 4; ++ks) {
        bf16x8 bv[2];
#pragma unroll
        for (int ni = 0; ni < 2; ++ni)
          bv[ni] = *(const bf16x8*)
              &Bp[(wn + ni * 32 + l31) * BK + (((ks * 2 + l5) ^ l7)) * 8];
#pragma unroll
        for (int mi = 0; mi < 2; ++mi)
#pragma unroll
          for (int ni = 0; ni < 2; ++ni)
            part[mi][ni] = __builtin_amdgcn_mfma_f32_32x32x16_bf16(
                af[ks][mi], bv[ni], (ks == 0) ? vz : part[mi][ni], 0, 0, 0);
      }

      // ---- FOLD: acc += c[row,e] * (part + (h==7)*beta[e,col]) ----
      // 32x32 C/D layout (m74/m101): col = lane&31,
      // row = (reg&3) + 8*(reg>>2) + 4*(lane>>5)
#pragma unroll
      for (int mi = 0; mi < 2; ++mi) {
        f32x4 cv[4];
#pragma unroll
        for (int g = 0; g < 4; ++g)
          cv[g] = *(const f32x4*)&cS[e * BM + wm + mi * 32 + g * 8 + l5 * 4];
#pragma unroll
        for (int ni = 0; ni < 2; ++ni) {
          const float bb = (h == 7) ? ebS[e * BN + wn + ni * 32 + l31] : 0.f;
#pragma unroll
          for (int g = 0; g < 4; ++g)
#pragma unroll
            for (int j = 0; j < 4; ++j)
              acc[mi][ni][g * 4 + j] +=
                  cv[g][j] * (part[mi][ni][g * 4 + j] + bb);
        }
      }
      __syncthreads();   // drains this t's staging loads; guards buffer swap
    }
  }

  // ---- epilogue: store acc (bias already folded) ----
#pragma unroll
  for (int mi = 0; mi < 2; ++mi) {
#pragma unroll
    for (int ni = 0; ni < 2; ++ni) {
      const int col = n0 + wn + ni * 32 + l31;
#pragma unroll
      for (int g = 0; g < 4; ++g)
#pragma unroll
        for (int j = 0; j < 4; ++j) {
          const int row = m0 + wm + mi * 32 + g * 8 + l5 * 4 + j;
          out[(size_t)row * DOUT + col] = acc[mi][ni][g * 4 + j];
        }
    }
  }
}

// ---------------------------------------------------------------------------
extern "C" void kernel_launch(void* const* d_in, const int* in_sizes, int n_in,
                              void* d_out, int out_size, void* d_ws,
                              size_t ws_size, hipStream_t stream) {
  (void)in_sizes; (void)n_in; (void)out_size; (void)ws_size;
  const float* x  = (const float*)d_in[0];   // [4,4096,512]
  const float* ew = (const float*)d_in[1];   // [8,512,512]
  const float* eb = (const float*)d_in[2];   // [8,512]
  const float* mw = (const float*)d_in[3];   // [8,512]
  const float* mb = (const float*)d_in[4];   // [8]
  float* out = (float*)d_out;                // [4,4096,512]

  // workspace layout: xbf 16 MB | wbf 4 MB | coeffsT 0.5 MB  (~20.5 MB)
  u16* xbf = (u16*)d_ws;
  u16* wbf = (u16*)((char*)d_ws + (size_t)NTOK * DIN * 2);
  float* coeffsT =
      (float*)((char*)d_ws + (size_t)NTOK * DIN * 2 + (size_t)KE * DOUT * DIN * 2);

  hipLaunchKernelGGL(gate_kernel, dim3(GATE_BLOCKS), dim3(256), 0, stream,
                     x, mw, mb, xbf, coeffsT);
  hipLaunchKernelGGL(wcast_kernel, dim3(WCONV_BLOCKS), dim3(256), 0, stream,
                     ew, wbf);
  hipLaunchKernelGGL(moe_gemm_kernel, dim3(512), dim3(256),
                     0, stream, xbf, wbf, coeffsT, eb, out);
}

// Round 3
// 318.092 us; speedup vs baseline: 6.0643x; 6.0643x over previous
//
#include <hip/hip_runtime.h>
#include <stdint.h>

#define NTOK 16384   // B*S = 4*4096
#define DIN 512
#define DOUT 512
#define KE 8
#define BM 128
#define BN 128
#define BK 64
#define ESTRIDE (DOUT * DIN)

#define GATE_BLOCKS 4096           // 1 token/wave, 4 waves/block
#define WCONV_BLOCKS 1024          // 2M elements / (256*8)

typedef unsigned short u16;
typedef u16 u16x8 __attribute__((ext_vector_type(8)));
typedef __bf16 bf16x8 __attribute__((ext_vector_type(8)));
typedef float f32x4 __attribute__((ext_vector_type(4)));
typedef float f32x16 __attribute__((ext_vector_type(16)));

__device__ __forceinline__ u16 f2bf(float f) {
  union { float f; unsigned u; } v; v.f = f;
  unsigned r = v.u + 0x7FFFu + ((v.u >> 16) & 1u);   // RNE; inputs are finite
  return (u16)(r >> 16);
}

// async global->LDS, 16B per lane; LDS dest is wave-uniform base + lane*16
#define GLOAD_LDS16(gp, lp)                                              \
  __builtin_amdgcn_global_load_lds(                                     \
      (__attribute__((address_space(1))) void*)(gp),                    \
      (__attribute__((address_space(3))) void*)(lp), 16, 0, 0)

// ---------------------------------------------------------------------------
// Kernel 1a: gating softmax + x fp32->bf16 cast. One token per wave.
// Coeffs written TRANSPOSED: coeffsT[e][tok].
// ---------------------------------------------------------------------------
__global__ __launch_bounds__(256) void gate_kernel(
    const float* __restrict__ x, const float* __restrict__ mw,
    const float* __restrict__ mb, u16* __restrict__ xbf,
    float* __restrict__ coeffsT) {
  const int tid = threadIdx.x;
  const int wave = tid >> 6, lane = tid & 63;
  const int tok = blockIdx.x * 4 + wave;

  // mixer weight slice for this lane, in registers (broadcast loads)
  float mwr[KE][8];
#pragma unroll
  for (int k = 0; k < KE; ++k) {
    const float* wr = &mw[k * DIN + lane * 8];
    const float4 w0 = *(const float4*)wr;
    const float4 w1 = *(const float4*)(wr + 4);
    mwr[k][0] = w0.x; mwr[k][1] = w0.y; mwr[k][2] = w0.z; mwr[k][3] = w0.w;
    mwr[k][4] = w1.x; mwr[k][5] = w1.y; mwr[k][6] = w1.z; mwr[k][7] = w1.w;
  }
  float mbr[KE];
#pragma unroll
  for (int k = 0; k < KE; ++k) mbr[k] = mb[k];

  const float* xr = x + (size_t)tok * DIN + lane * 8;
  const float4 xa = *(const float4*)xr;
  const float4 xb = *(const float4*)(xr + 4);

  u16x8 p;
  p[0] = f2bf(xa.x); p[1] = f2bf(xa.y); p[2] = f2bf(xa.z); p[3] = f2bf(xa.w);
  p[4] = f2bf(xb.x); p[5] = f2bf(xb.y); p[6] = f2bf(xb.z); p[7] = f2bf(xb.w);
  *(u16x8*)(xbf + (size_t)tok * DIN + lane * 8) = p;

  float lg[KE];
#pragma unroll
  for (int k = 0; k < KE; ++k) {
    lg[k] = xa.x * mwr[k][0] + xa.y * mwr[k][1] + xa.z * mwr[k][2] +
            xa.w * mwr[k][3] + xb.x * mwr[k][4] + xb.y * mwr[k][5] +
            xb.z * mwr[k][6] + xb.w * mwr[k][7];
  }
#pragma unroll
  for (int off = 32; off; off >>= 1)
#pragma unroll
    for (int k = 0; k < KE; ++k) lg[k] += __shfl_xor(lg[k], off);

#pragma unroll
  for (int k = 0; k < KE; ++k) lg[k] += mbr[k];
  float mx = lg[0];
#pragma unroll
  for (int k = 1; k < KE; ++k) mx = fmaxf(mx, lg[k]);
  float s = 0.f;
#pragma unroll
  for (int k = 0; k < KE; ++k) { lg[k] = __expf(lg[k] - mx); s += lg[k]; }
  const float inv = 1.f / s;
  if (lane == 0) {
#pragma unroll
    for (int k = 0; k < KE; ++k) coeffsT[(size_t)k * NTOK + tok] = lg[k] * inv;
  }
}

// ---------------------------------------------------------------------------
// Kernel 1b: expert-weight fp32->bf16 cast (8 elements/thread).
// ---------------------------------------------------------------------------
__global__ __launch_bounds__(256) void wcast_kernel(
    const float* __restrict__ ew, u16* __restrict__ wbf) {
  const size_t i = ((size_t)blockIdx.x * 256 + threadIdx.x) * 8;
  const float4 a = *(const float4*)&ew[i];
  const float4 b = *(const float4*)&ew[i + 4];
  u16x8 p;
  p[0] = f2bf(a.x); p[1] = f2bf(a.y); p[2] = f2bf(a.z); p[3] = f2bf(a.w);
  p[4] = f2bf(b.x); p[5] = f2bf(b.y); p[6] = f2bf(b.z); p[7] = f2bf(b.w);
  *(u16x8*)&wbf[i] = p;
}

// ---------------------------------------------------------------------------
// Kernel 2: MoE GEMM v4. h-outer / e-inner (keeps R2's A-traffic win:
// A staged once per K-chunk, B streams L2-resident per XCD).
// R2 post-mortem: WRITE_SIZE 3.7 GB = accumulator SPILL inside the t-loop
// (acc64+part64+af32+misc > the 128-VGPR allocation). v4 fixes pressure:
//  - fold per-ni: pp[2] (32 regs) instead of part[2][2] (64)
//  - bias moved to epilogue (Sum_e c_e*beta_e), no (h==7) operand in loop
//  - __launch_bounds__(256) only: allocator may NOT spill to hit a cap;
//    LDS 56 KB pins 2 blocks/CU regardless.
// Peak live ~215 regs < 256.
// Swizzle v2 (both-sides rule): LDS slot s of row r holds global chunk
// s ^ (r&7) ^ ((r>>3)&3)  -- spreads the 4 same-slot lanes of each 32-lane
// fragment-read group across distinct bank slots (R2: 4.7M conflicts).
// One barrier per t (T3 minimum 2-phase: stage -> compute -> barrier).
// ---------------------------------------------------------------------------
__global__ __launch_bounds__(256) void moe_gemm_kernel(
    const u16* __restrict__ xbf, const u16* __restrict__ wbf,
    const float* __restrict__ coeffsT, const float* __restrict__ ebias,
    float* __restrict__ out) {
  __shared__ __align__(16) u16 As[BM * BK];        // 16 KB, single buffer
  __shared__ __align__(16) u16 Bs[2][BN * BK];     // 2 x 16 KB
  __shared__ __align__(16) float cS[KE * BM];      // 4 KB  coeffs slice
  __shared__ __align__(16) float ebS[KE * BN];     // 4 KB  bias slice

  const int tid = threadIdx.x;
  const int wave = tid >> 6, lane = tid & 63;

  // XCD swizzle: b&7 = xcd. Each XCD-pair owns one n-column -> its 1 MB
  // B slice is L2-resident.
  const int b = blockIdx.x;
  const int xcd = b & 7, sq = b >> 3;           // sq in [0,64)
  const int m0 = ((xcd & 1) * 64 + sq) * BM;
  const int n0 = (xcd >> 1) * BN;

  const int wm = (wave >> 1) * 64;   // wave's row offset: {0,64}
  const int wn = (wave & 1) * 64;    // wave's col offset: {0,64}

  const int l31 = lane & 31, l5 = lane >> 5, l7 = lane & 7;
  const int lrow = lane >> 3;
  // read-side swizzle key: (row&7) ^ ((row>>3)&3) for row = wm+mi*32+l31
  const int swz = l7 ^ ((lane >> 3) & 3);

  // staging base pointers, one per GLOAD j (source col pre-swizzled;
  // swizzle key depends on j via the chunk-row index (wave*4+j)&3)
  const u16* aB[4];
  const u16* bB[4];
#pragma unroll
  for (int j = 0; j < 4; ++j) {
    const int row = wave * 32 + j * 8 + lrow;
    const int sc = (l7 ^ lrow ^ ((wave * 4 + j) & 3)) * 8;
    aB[j] = xbf + (size_t)(m0 + row) * DIN + sc;
    bB[j] = wbf + (size_t)(n0 + row) * DIN + sc;
  }

  // ---- prologue staging: A_0, B_0, coeffs slice, bias slice ----
#pragma unroll
  for (int j = 0; j < 4; ++j)
    GLOAD_LDS16(aB[j], &As[(wave * 32 + j * 8) * BK]);
#pragma unroll
  for (int j = 0; j < 4; ++j)
    GLOAD_LDS16(bB[j], &Bs[0][(wave * 32 + j * 8) * BK]);
  // cS[e][i] = coeffsT[e][m0+i]; wave w covers e in {2w,2w+1}
  GLOAD_LDS16(coeffsT + (size_t)(wave * 2 + l5) * NTOK + m0 + l31 * 4,
              &cS[wave * 256]);
  GLOAD_LDS16(ebias + (size_t)(wave * 2 + l5) * DOUT + n0 + l31 * 4,
              &ebS[wave * 256]);
  __syncthreads();

  const f32x16 vz = {};
  f32x16 acc[2][2] = {{vz, vz}, {vz, vz}};
  bf16x8 af[4][2];   // A fragments for current h chunk: [ks][mi]

  for (int h = 0; h < 8; ++h) {
    for (int e = 0; e < KE; ++e) {
      const int t = h * 8 + e;

      // ---- STAGE next B tile (and A_{h+1} at e==1) ----
      if (t < 63) {
        const int tn = t + 1;
        const size_t off =
            (size_t)(tn & 7) * ESTRIDE + (size_t)(tn >> 3) * 64;
#pragma unroll
        for (int j = 0; j < 4; ++j)
          GLOAD_LDS16(bB[j] + off, &Bs[tn & 1][(wave * 32 + j * 8) * BK]);
      }
      if (e == 1 && h < 7) {
#pragma unroll
        for (int j = 0; j < 4; ++j)
          GLOAD_LDS16(aB[j] + (size_t)(h + 1) * 64,
                      &As[(wave * 32 + j * 8) * BK]);
      }

      // ---- A fragments (tile h) once per h, at e==0 ----
      if (e == 0) {
#pragma unroll
        for (int ks = 0; ks < 4; ++ks)
#pragma unroll
          for (int mi = 0; mi < 2; ++mi)
            af[ks][mi] = *(const bf16x8*)
                &As[(wm + mi * 32 + l31) * BK + ((ks * 2 + l5) ^ swz) * 8];
      }

      // per-t coefficient registers (broadcast LDS reads)
      f32x4 cv[2][4];
#pragma unroll
      for (int mi = 0; mi < 2; ++mi)
#pragma unroll
        for (int g = 0; g < 4; ++g)
          cv[mi][g] =
              *(const f32x4*)&cS[e * BM + wm + mi * 32 + g * 8 + l5 * 4];

      // ---- COMPUTE + FOLD, one ni column-group at a time ----
      const u16* Bp = Bs[t & 1];
#pragma unroll
      for (int ni = 0; ni < 2; ++ni) {
        bf16x8 bv[4];
#pragma unroll
        for (int ks = 0; ks < 4; ++ks)
          bv[ks] = *(const bf16x8*)
              &Bp[(wn + ni * 32 + l31) * BK + ((ks * 2 + l5) ^ swz) * 8];
        f32x16 pp[2];
#pragma unroll
        for (int ks = 0; ks < 4; ++ks)
#pragma unroll
          for (int mi = 0; mi < 2; ++mi)
            pp[mi] = __builtin_amdgcn_mfma_f32_32x32x16_bf16(
                af[ks][mi], bv[ks], (ks == 0) ? vz : pp[mi], 0, 0, 0);
        // 32x32 C/D layout (m74/m101): col = lane&31,
        // row = (reg&3) + 8*(reg>>2) + 4*(lane>>5)
#pragma unroll
        for (int mi = 0; mi < 2; ++mi)
#pragma unroll
          for (int g = 0; g < 4; ++g)
#pragma unroll
            for (int j2 = 0; j2 < 4; ++j2)
              acc[mi][ni][g * 4 + j2] += cv[mi][g][j2] * pp[mi][g * 4 + j2];
      }
      __syncthreads();   // separates reads of Bs[t&1] from t+1's overwrite
    }
  }

  // ---- epilogue: bias fold  acc += Sum_e c[e][row] * beta[e][col] ----
#pragma unroll
  for (int e = 0; e < KE; ++e) {
    const float eb0 = ebS[e * BN + wn + l31];
    const float eb1 = ebS[e * BN + wn + 32 + l31];
#pragma unroll
    for (int mi = 0; mi < 2; ++mi)
#pragma unroll
      for (int g = 0; g < 4; ++g) {
        const f32x4 c4 =
            *(const f32x4*)&cS[e * BM + wm + mi * 32 + g * 8 + l5 * 4];
#pragma unroll
        for (int j2 = 0; j2 < 4; ++j2) {
          acc[mi][0][g * 4 + j2] += c4[j2] * eb0;
          acc[mi][1][g * 4 + j2] += c4[j2] * eb1;
        }
      }
  }

  // ---- stores ----
#pragma unroll
  for (int mi = 0; mi < 2; ++mi)
#pragma unroll
    for (int ni = 0; ni < 2; ++ni) {
      const int col = n0 + wn + ni * 32 + l31;
#pragma unroll
      for (int g = 0; g < 4; ++g)
#pragma unroll
        for (int j2 = 0; j2 < 4; ++j2) {
          const int row = m0 + wm + mi * 32 + g * 8 + l5 * 4 + j2;
          out[(size_t)row * DOUT + col] = acc[mi][ni][g * 4 + j2];
        }
    }
}

// ---------------------------------------------------------------------------
extern "C" void kernel_launch(void* const* d_in, const int* in_sizes, int n_in,
                              void* d_out, int out_size, void* d_ws,
                              size_t ws_size, hipStream_t stream) {
  (void)in_sizes; (void)n_in; (void)out_size; (void)ws_size;
  const float* x  = (const float*)d_in[0];   // [4,4096,512]
  const float* ew = (const float*)d_in[1];   // [8,512,512]
  const float* eb = (const float*)d_in[2];   // [8,512]
  const float* mw = (const float*)d_in[3];   // [8,512]
  const float* mb = (const float*)d_in[4];   // [8]
  float* out = (float*)d_out;                // [4,4096,512]

  // workspace layout: xbf 16 MB | wbf 4 MB | coeffsT 0.5 MB  (~20.5 MB)
  u16* xbf = (u16*)d_ws;
  u16* wbf = (u16*)((char*)d_ws + (size_t)NTOK * DIN * 2);
  float* coeffsT =
      (float*)((char*)d_ws + (size_t)NTOK * DIN * 2 + (size_t)KE * DOUT * DIN * 2);

  hipLaunchKernelGGL(gate_kernel, dim3(GATE_BLOCKS), dim3(256), 0, stream,
                     x, mw, mb, xbf, coeffsT);
  hipLaunchKernelGGL(wcast_kernel, dim3(WCONV_BLOCKS), dim3(256), 0, stream,
                     ew, wbf);
  hipLaunchKernelGGL(moe_gemm_kernel, dim3(512), dim3(256),
                     0, stream, xbf, wbf, coeffsT, eb, out);
}

// Round 4
// 229.698 us; speedup vs baseline: 8.3979x; 1.3848x over previous
//
#include <hip/hip_runtime.h>
#include <stdint.h>

#define NTOK 16384   // B*S = 4*4096
#define DIN 512
#define DOUT 512
#define KE 8
#define BM 128
#define BN 128
#define BK 64
#define ESTRIDE (DOUT * DIN)

#define GATE_BLOCKS 4096           // 1 token/wave, 4 waves/block
#define WCONV_BLOCKS 1024          // 2M elements / (256*8)

typedef unsigned short u16;
typedef u16 u16x8 __attribute__((ext_vector_type(8)));
typedef __bf16 bf16x8 __attribute__((ext_vector_type(8)));
typedef float f32x4 __attribute__((ext_vector_type(4)));
typedef float f32x16 __attribute__((ext_vector_type(16)));

__device__ __forceinline__ u16 f2bf(float f) {
  union { float f; unsigned u; } v; v.f = f;
  unsigned r = v.u + 0x7FFFu + ((v.u >> 16) & 1u);   // RNE; inputs are finite
  return (u16)(r >> 16);
}

// async global->LDS, 16B per lane; LDS dest is wave-uniform base + lane*16
#define GLOAD_LDS16(gp, lp)                                              \
  __builtin_amdgcn_global_load_lds(                                     \
      (__attribute__((address_space(1))) void*)(gp),                    \
      (__attribute__((address_space(3))) void*)(lp), 16, 0, 0)

// ---------------------------------------------------------------------------
// Kernel 1a: gating softmax + x fp32->bf16 cast. One token per wave.
// Coeffs written TRANSPOSED: coeffsT[e][tok].
// ---------------------------------------------------------------------------
__global__ __launch_bounds__(256) void gate_kernel(
    const float* __restrict__ x, const float* __restrict__ mw,
    const float* __restrict__ mb, u16* __restrict__ xbf,
    float* __restrict__ coeffsT) {
  const int tid = threadIdx.x;
  const int wave = tid >> 6, lane = tid & 63;
  const int tok = blockIdx.x * 4 + wave;

  // mixer weight slice for this lane, in registers (broadcast loads)
  float mwr[KE][8];
#pragma unroll
  for (int k = 0; k < KE; ++k) {
    const float* wr = &mw[k * DIN + lane * 8];
    const float4 w0 = *(const float4*)wr;
    const float4 w1 = *(const float4*)(wr + 4);
    mwr[k][0] = w0.x; mwr[k][1] = w0.y; mwr[k][2] = w0.z; mwr[k][3] = w0.w;
    mwr[k][4] = w1.x; mwr[k][5] = w1.y; mwr[k][6] = w1.z; mwr[k][7] = w1.w;
  }
  float mbr[KE];
#pragma unroll
  for (int k = 0; k < KE; ++k) mbr[k] = mb[k];

  const float* xr = x + (size_t)tok * DIN + lane * 8;
  const float4 xa = *(const float4*)xr;
  const float4 xb = *(const float4*)(xr + 4);

  u16x8 p;
  p[0] = f2bf(xa.x); p[1] = f2bf(xa.y); p[2] = f2bf(xa.z); p[3] = f2bf(xa.w);
  p[4] = f2bf(xb.x); p[5] = f2bf(xb.y); p[6] = f2bf(xb.z); p[7] = f2bf(xb.w);
  *(u16x8*)(xbf + (size_t)tok * DIN + lane * 8) = p;

  float lg[KE];
#pragma unroll
  for (int k = 0; k < KE; ++k) {
    lg[k] = xa.x * mwr[k][0] + xa.y * mwr[k][1] + xa.z * mwr[k][2] +
            xa.w * mwr[k][3] + xb.x * mwr[k][4] + xb.y * mwr[k][5] +
            xb.z * mwr[k][6] + xb.w * mwr[k][7];
  }
#pragma unroll
  for (int off = 32; off; off >>= 1)
#pragma unroll
    for (int k = 0; k < KE; ++k) lg[k] += __shfl_xor(lg[k], off);

#pragma unroll
  for (int k = 0; k < KE; ++k) lg[k] += mbr[k];
  float mx = lg[0];
#pragma unroll
  for (int k = 1; k < KE; ++k) mx = fmaxf(mx, lg[k]);
  float s = 0.f;
#pragma unroll
  for (int k = 0; k < KE; ++k) { lg[k] = __expf(lg[k] - mx); s += lg[k]; }
  const float inv = 1.f / s;
  if (lane == 0) {
#pragma unroll
    for (int k = 0; k < KE; ++k) coeffsT[(size_t)k * NTOK + tok] = lg[k] * inv;
  }
}

// ---------------------------------------------------------------------------
// Kernel 1b: expert-weight fp32->bf16 cast (8 elements/thread).
// ---------------------------------------------------------------------------
__global__ __launch_bounds__(256) void wcast_kernel(
    const float* __restrict__ ew, u16* __restrict__ wbf) {
  const size_t i = ((size_t)blockIdx.x * 256 + threadIdx.x) * 8;
  const float4 a = *(const float4*)&ew[i];
  const float4 b = *(const float4*)&ew[i + 4];
  u16x8 p;
  p[0] = f2bf(a.x); p[1] = f2bf(a.y); p[2] = f2bf(a.z); p[3] = f2bf(a.w);
  p[4] = f2bf(b.x); p[5] = f2bf(b.y); p[6] = f2bf(b.z); p[7] = f2bf(b.w);
  *(u16x8*)&wbf[i] = p;
}

// ---------------------------------------------------------------------------
// Kernel 2: MoE GEMM v5. h-outer / e-inner (A staged once per K-chunk,
// B streams L2-resident per XCD) -- kept from v4.
// R3 post-mortem: VGPR=256 + WRITE 282 MB = still spilling. Cause: the
// fold needed cv[2][4] (32 regs) because C/D row = token. v5 SWAPS the
// MFMA operands (A=W rows, B=X rows -> D[o, token], col=lane&31=token):
//  - coefficient becomes a per-lane SCALAR (2 ds_read_b32 per t)
//  - X fragments resident per h (32 regs); W fragments transient (16)
//  - fold: acc[oi][ti] += c_ti * pp   (scalar multiplier)
// Peak live ~160 regs -> no spill. LDS read patterns byte-identical to
// v4 (A/B fragment layouts are symmetric); only operand order, fold and
// store addressing changed. Swizzle (0 conflicts in R3) unchanged:
// slot s of row r holds global chunk s ^ (r&7) ^ ((r>>3)&3), both sides.
// One barrier per t. Bias folded in epilogue: acc += Sum_e c_e*beta_e.
// ---------------------------------------------------------------------------
__global__ __launch_bounds__(256) void moe_gemm_kernel(
    const u16* __restrict__ xbf, const u16* __restrict__ wbf,
    const float* __restrict__ coeffsT, const float* __restrict__ ebias,
    float* __restrict__ out) {
  __shared__ __align__(16) u16 As[BM * BK];        // 16 KB, single buffer (X)
  __shared__ __align__(16) u16 Bs[2][BN * BK];     // 2 x 16 KB (W, dbuf)
  __shared__ __align__(16) float cS[KE * BM];      // 4 KB  coeffs slice
  __shared__ __align__(16) float ebS[KE * BN];     // 4 KB  bias slice

  const int tid = threadIdx.x;
  const int wave = tid >> 6, lane = tid & 63;

  // XCD swizzle: b&7 = xcd. Each XCD-pair owns one n-column -> its 1 MB
  // B slice is L2-resident.
  const int b = blockIdx.x;
  const int xcd = b & 7, sq = b >> 3;           // sq in [0,64)
  const int m0 = ((xcd & 1) * 64 + sq) * BM;    // token base
  const int n0 = (xcd >> 1) * BN;               // dout base

  const int wt = (wave >> 1) * 64;   // wave's token offset: {0,64}
  const int wo = (wave & 1) * 64;    // wave's dout  offset: {0,64}

  const int l31 = lane & 31, l5 = lane >> 5, l7 = lane & 7;
  const int lrow = lane >> 3;
  // read-side swizzle key: (row&7) ^ ((row>>3)&3) for row = base+l31
  const int swz = l7 ^ ((lane >> 3) & 3);

  // staging base pointers (source col pre-swizzled; key = l7^lrow^j)
  const u16* aB[4];
  const u16* bB[4];
#pragma unroll
  for (int j = 0; j < 4; ++j) {
    const int row = wave * 32 + j * 8 + lrow;
    const int sc = (l7 ^ lrow ^ ((wave * 4 + j) & 3)) * 8;
    aB[j] = xbf + (size_t)(m0 + row) * DIN + sc;
    bB[j] = wbf + (size_t)(n0 + row) * DIN + sc;
  }

  // ---- prologue staging: X_0, W_0, coeffs slice, bias slice ----
#pragma unroll
  for (int j = 0; j < 4; ++j)
    GLOAD_LDS16(aB[j], &As[(wave * 32 + j * 8) * BK]);
#pragma unroll
  for (int j = 0; j < 4; ++j)
    GLOAD_LDS16(bB[j], &Bs[0][(wave * 32 + j * 8) * BK]);
  // cS[e][i] = coeffsT[e][m0+i]; wave w covers e in {2w,2w+1}
  GLOAD_LDS16(coeffsT + (size_t)(wave * 2 + l5) * NTOK + m0 + l31 * 4,
              &cS[wave * 256]);
  GLOAD_LDS16(ebias + (size_t)(wave * 2 + l5) * DOUT + n0 + l31 * 4,
              &ebS[wave * 256]);
  __syncthreads();

  const f32x16 vz = {};
  f32x16 acc[2][2] = {{vz, vz}, {vz, vz}};   // [oi][ti]
  bf16x8 xf[4][2];   // X fragments for current h chunk: [ks][ti]

  for (int h = 0; h < 8; ++h) {
#pragma unroll 2
    for (int e = 0; e < KE; ++e) {
      const int t = h * 8 + e;

      // ---- STAGE next W tile (and X_{h+1} at e==1) ----
      if (t < 63) {
        const int tn = t + 1;
        const size_t off =
            (size_t)(tn & 7) * ESTRIDE + (size_t)(tn >> 3) * 64;
#pragma unroll
        for (int j = 0; j < 4; ++j)
          GLOAD_LDS16(bB[j] + off, &Bs[tn & 1][(wave * 32 + j * 8) * BK]);
      }
      if (e == 1 && h < 7) {
#pragma unroll
        for (int j = 0; j < 4; ++j)
          GLOAD_LDS16(aB[j] + (size_t)(h + 1) * 64,
                      &As[(wave * 32 + j * 8) * BK]);
      }

      // ---- X fragments (tile h) once per h, at e==0 ----
      if (e == 0) {
#pragma unroll
        for (int ks = 0; ks < 4; ++ks)
#pragma unroll
          for (int ti = 0; ti < 2; ++ti)
            xf[ks][ti] = *(const bf16x8*)
                &As[(wt + ti * 32 + l31) * BK + ((ks * 2 + l5) ^ swz) * 8];
      }

      // per-t coefficient scalars (per-lane; lanes 32-63 broadcast-alias)
      const float cv0 = cS[e * BM + wt + l31];
      const float cv1 = cS[e * BM + wt + 32 + l31];

      // ---- COMPUTE + FOLD: D[o, token], one oi row-group at a time ----
      const u16* Bp = Bs[t & 1];
#pragma unroll
      for (int oi = 0; oi < 2; ++oi) {
        bf16x8 wf[4];
#pragma unroll
        for (int ks = 0; ks < 4; ++ks)
          wf[ks] = *(const bf16x8*)
              &Bp[(wo + oi * 32 + l31) * BK + ((ks * 2 + l5) ^ swz) * 8];
#pragma unroll
        for (int ti = 0; ti < 2; ++ti) {
          f32x16 pp;
#pragma unroll
          for (int ks = 0; ks < 4; ++ks)
            pp = __builtin_amdgcn_mfma_f32_32x32x16_bf16(
                wf[ks], xf[ks][ti], (ks == 0) ? vz : pp, 0, 0, 0);
          const float c = (ti == 0) ? cv0 : cv1;
#pragma unroll
          for (int r = 0; r < 16; ++r) acc[oi][ti][r] += c * pp[r];
        }
      }
      __syncthreads();   // separates reads of Bs[t&1] from t+1's overwrite
    }
  }

  // ---- epilogue: bias fold  acc[o,tok] += Sum_e c[e][tok] * beta[e][o] ----
#pragma unroll
  for (int e = 0; e < KE; ++e) {
    const float cv0 = cS[e * BM + wt + l31];
    const float cv1 = cS[e * BM + wt + 32 + l31];
#pragma unroll
    for (int oi = 0; oi < 2; ++oi)
#pragma unroll
      for (int g = 0; g < 4; ++g) {
        const f32x4 bb =
            *(const f32x4*)&ebS[e * BN + wo + oi * 32 + g * 8 + l5 * 4];
#pragma unroll
        for (int j2 = 0; j2 < 4; ++j2) {
          acc[oi][0][g * 4 + j2] += cv0 * bb[j2];
          acc[oi][1][g * 4 + j2] += cv1 * bb[j2];
        }
      }
  }

  // ---- stores: out[token, o]; token = col = l31, o = row (contig in j2) ----
#pragma unroll
  for (int oi = 0; oi < 2; ++oi)
#pragma unroll
    for (int ti = 0; ti < 2; ++ti) {
      const size_t rowbase = (size_t)(m0 + wt + ti * 32 + l31) * DOUT;
#pragma unroll
      for (int g = 0; g < 4; ++g) {
        f32x4 v;
#pragma unroll
        for (int j2 = 0; j2 < 4; ++j2) v[j2] = acc[oi][ti][g * 4 + j2];
        *(f32x4*)&out[rowbase + n0 + wo + oi * 32 + g * 8 + l5 * 4] = v;
      }
    }
}

// ---------------------------------------------------------------------------
extern "C" void kernel_launch(void* const* d_in, const int* in_sizes, int n_in,
                              void* d_out, int out_size, void* d_ws,
                              size_t ws_size, hipStream_t stream) {
  (void)in_sizes; (void)n_in; (void)out_size; (void)ws_size;
  const float* x  = (const float*)d_in[0];   // [4,4096,512]
  const float* ew = (const float*)d_in[1];   // [8,512,512]
  const float* eb = (const float*)d_in[2];   // [8,512]
  const float* mw = (const float*)d_in[3];   // [8,512]
  const float* mb = (const float*)d_in[4];   // [8]
  float* out = (float*)d_out;                // [4,4096,512]

  // workspace layout: xbf 16 MB | wbf 4 MB | coeffsT 0.5 MB  (~20.5 MB)
  u16* xbf = (u16*)d_ws;
  u16* wbf = (u16*)((char*)d_ws + (size_t)NTOK * DIN * 2);
  float* coeffsT =
      (float*)((char*)d_ws + (size_t)NTOK * DIN * 2 + (size_t)KE * DOUT * DIN * 2);

  hipLaunchKernelGGL(gate_kernel, dim3(GATE_BLOCKS), dim3(256), 0, stream,
                     x, mw, mb, xbf, coeffsT);
  hipLaunchKernelGGL(wcast_kernel, dim3(WCONV_BLOCKS), dim3(256), 0, stream,
                     ew, wbf);
  hipLaunchKernelGGL(moe_gemm_kernel, dim3(512), dim3(256),
                     0, stream, xbf, wbf, coeffsT, eb, out);
}